// Round 14
// baseline (480.960 us; speedup 1.0000x reference)
//
#include <hip/hip_runtime.h>
#include <stdint.h>

typedef short  short8  __attribute__((ext_vector_type(8)));
typedef unsigned short ushort8 __attribute__((ext_vector_type(8)));
typedef unsigned short ushort4v __attribute__((ext_vector_type(4)));
typedef float  f32x4   __attribute__((ext_vector_type(4)));
typedef float  f32x16  __attribute__((ext_vector_type(16)));

#define BB  4
#define SQL 2048
#define SKL 2048
#define NEGV -1e9f
#define AS1 __attribute__((address_space(1)))
#define AS3 __attribute__((address_space(3)))

__device__ __forceinline__ unsigned short f2bf(float f){
  union { float f; uint32_t u; } x; x.f = f;
  return (unsigned short)((x.u + 0x7FFFu + ((x.u >> 16) & 1u)) >> 16);
}
__device__ __forceinline__ float bf2f(unsigned short h){
  union { uint32_t u; float f; } x; x.u = ((uint32_t)h) << 16;
  return x.f;
}

#define BARR() __builtin_amdgcn_s_barrier()
#define LGKM0() asm volatile("s_waitcnt lgkmcnt(0)" ::: "memory")
#define LGKMW(N) asm volatile("s_waitcnt lgkmcnt(" #N ")" ::: "memory")
#define VMW(N)  asm volatile("s_waitcnt vmcnt(" #N ")"   ::: "memory")
#define PRIO1 __builtin_amdgcn_s_setprio(1)
#define PRIO0 __builtin_amdgcn_s_setprio(0)

// ---------------- mask dtype sniffing ----------------
__global__ void mask_detect(const uint8_t* __restrict__ m, int* __restrict__ cnt){
  const long n4 = (long)BB * SQL * SKL / 4;
  long idx  = (long)blockIdx.x * blockDim.x + threadIdx.x;
  long step = (long)gridDim.x * blockDim.x;
  int c0 = 0, c1 = 0, c2 = 0;
  for (long i4 = idx; i4 < n4; i4 += step){
    uchar4 b = ((const uchar4*)m)[i4];
    c0 += (b.y != 0) + (b.z != 0) + (b.w != 0);
    c1 += (b.x > 1) + (b.y > 1) + (b.z > 1) + (b.w > 1);
    c2 += (b.y != 0);
  }
  #pragma unroll
  for (int o = 32; o >= 1; o >>= 1){
    c0 += __shfl_xor(c0, o); c1 += __shfl_xor(c1, o); c2 += __shfl_xor(c2, o);
  }
  if ((threadIdx.x & 63) == 0){
    atomicAdd(&cnt[0], c0); atomicAdd(&cnt[1], c1); atomicAdd(&cnt[2], c2);
  }
}

// ------ prep: fused {f32->bf16 cvt of x, enc_q, enc_k, Wv} + {transpose-cvt Wq, Wk} ------
__global__ __launch_bounds__(256)
void prep(const float* __restrict__ s0, const float* __restrict__ s1,
          const float* __restrict__ s2, const float* __restrict__ s3,
          unsigned short* __restrict__ d0, unsigned short* __restrict__ d1,
          unsigned short* __restrict__ d2, unsigned short* __restrict__ d3,
          const float* __restrict__ tq, const float* __restrict__ tk,
          unsigned short* __restrict__ dq, unsigned short* __restrict__ dk)
{
  if (blockIdx.x < 2048){
    const long total = 6815744;  // 3*2097152 + 524288 chunks of 8
    for (long c = (long)blockIdx.x * 256 + threadIdx.x; c < total; c += 2048 * 256){
      const float* s; unsigned short* d; long off;
      if      (c < 2097152){ s = s0; d = d0; off = c; }
      else if (c < 4194304){ s = s1; d = d1; off = c - 2097152; }
      else if (c < 6291456){ s = s2; d = d2; off = c - 4194304; }
      else                 { s = s3; d = d3; off = c - 6291456; }
      f32x4 a = ((const f32x4*)s)[off * 2];
      f32x4 b = ((const f32x4*)s)[off * 2 + 1];
      ushort8 w;
      #pragma unroll
      for (int j = 0; j < 4; ++j){ w[j] = f2bf(a[j]); w[j + 4] = f2bf(b[j]); }
      ((ushort8*)d)[off] = w;
    }
  } else {
    __shared__ float t[32][33];
    const int j = blockIdx.x - 2048;           // [0, 8192)
    const int z = j >> 12, rem = j & 4095;
    const float* s = z ? tk : tq;
    unsigned short* d = z ? dk : dq;
    const long bx = (long)(rem & 63) * 32, by = (long)(rem >> 6) * 32;
    const int tx = threadIdx.x & 31, ty = threadIdx.x >> 5;   // 32 x 8
    #pragma unroll
    for (int jj = 0; jj < 4; ++jj)
      t[ty + jj * 8][tx] = s[(by + ty + jj * 8) * 2048 + bx + tx];
    __syncthreads();
    #pragma unroll
    for (int jj = 0; jj < 4; ++jj)
      d[(bx + ty + jj * 8) * 2048 + by + tx] = f2bf(t[tx][ty + jj * 8]);
  }
}

// bijective XCD swizzle (nwg % 8 == 0 for all our grids)
__device__ __forceinline__ void xcd_decode(int& bx, int& by, int& bz){
  const int gx = gridDim.x, gy = gridDim.y;
  const int nwg = gx * gy * gridDim.z;
  const int lid = blockIdx.x + gx * (blockIdx.y + gy * blockIdx.z);
  const int sw  = (lid & 7) * (nwg >> 3) + (lid >> 3);
  bx = sw % gx;
  const int t = sw / gx;
  by = t % gy;
  bz = t / gy;
}

// ====== 256x256 NT GEMM — m201 schedule, 32x32x16 MFMA (2495 TF ceiling) ======
// Per wave 128x64 = [qm][qn][fa] frags of 32x32. A frag: lane row l&31,
// k=(l>>5)*8+j (doubling rule of the verified 16x16x32 mapping). C/D layout
// (m74/m101-verified): col=lane&31, row=(r&3)+8*(r>>2)+4*(lane>>5).
// Staging / vmcnt ledger identical to round-13 (passing, 454us).
// EPI: 0 = bf16 C (scaled); 2 = f32 C.
template<int EPI>
__device__ __forceinline__ void gemm256_body(
    const unsigned short* __restrict__ Ag, const unsigned short* __restrict__ Bg,
    void* __restrict__ Cb, int bz, long Cbs, long tm, long tn, float scale,
    unsigned short (&lA)[2][16384], unsigned short (&lB)[2][16384])
{
  constexpr int LD = 2048;
  const int tid = threadIdx.x, lane = tid & 63, wid = tid >> 6;
  const int wm = wid >> 2, wn = wid & 3;
  const int l31 = lane & 31, l32 = lane >> 5;

  f32x16 acc[2][2][2] = {};   // [qm][qn][fa]
  short8 aF[2][4];            // [fa][ks]  (current qm half)
  short8 bF[2][4];            // [qn][ks]  (both halves live)

  auto stageA = [&](int buf, int half, int k){
    const unsigned short* s = Ag + (tm + half * 128) * LD + k;
    unsigned short* d = lA[buf] + half * 8192;
    #pragma unroll
    for (int l = 0; l < 2; ++l){
      const int idx = l * 512 + tid;
      const int r   = idx >> 3;
      const int gsw = (idx & 7) ^ (r & 7);
      __builtin_amdgcn_global_load_lds((const AS1 void*)(s + r * LD + gsw * 8),
                                       (AS3 void*)(d + idx * 8), 16, 0, 0);
    }
  };
  auto stageB = [&](int buf, int half, int k){
    const unsigned short* s = Bg + (tn + half * 128) * LD + k;
    unsigned short* d = lB[buf] + half * 8192;
    #pragma unroll
    for (int l = 0; l < 2; ++l){
      const int idx = l * 512 + tid;
      const int r   = idx >> 3;
      const int gsw = (idx & 7) ^ (r & 7);
      __builtin_amdgcn_global_load_lds((const AS1 void*)(s + r * LD + gsw * 8),
                                       (AS3 void*)(d + idx * 8), 16, 0, 0);
    }
  };

  #define RD_A(BUF, QM)                                                       \
    _Pragma("unroll")                                                         \
    for (int fa = 0; fa < 2; ++fa)                                            \
      _Pragma("unroll")                                                       \
      for (int ks = 0; ks < 4; ++ks){                                         \
        const int r = (QM) * 128 + wm * 64 + fa * 32 + l31;                   \
        const int g = ks * 2 + l32;                                           \
        aF[fa][ks] = *(const short8*)&lA[(BUF)][(r * 8 + (g ^ (r & 7))) * 8]; \
      }
  #define RD_B(BUF, QN)                                                       \
    _Pragma("unroll")                                                         \
    for (int ks = 0; ks < 4; ++ks){                                           \
      const int c = (QN) * 128 + wn * 32 + l31;                               \
      const int g = ks * 2 + l32;                                             \
      bF[QN][ks] = *(const short8*)&lB[(BUF)][(c * 8 + (g ^ (c & 7))) * 8];   \
    }
  #define MFMA8(QM, QN)                                                       \
    _Pragma("unroll")                                                         \
    for (int ks = 0; ks < 4; ++ks)                                            \
      _Pragma("unroll")                                                       \
      for (int fa = 0; fa < 2; ++fa)                                          \
        acc[QM][QN][fa] = __builtin_amdgcn_mfma_f32_32x32x16_bf16(            \
            aF[fa][ks], bF[QN][ks], acc[QM][QN][fa], 0, 0, 0);

  // tile t in BUF; KN1 = (t+1)*64, KN2 = (t+2)*64
  #define KTILE_MAIN(BUF, KN1, KN2)                                           \
  {                                                                           \
    RD_A(BUF, 0); RD_B(BUF, 0);                                               \
    stageA((BUF) ^ 1, 1, (KN1));   /* A1(t+1): completes t+1 */               \
    LGKMW(8); BARR(); LGKM0();                                                \
    PRIO1; MFMA8(0, 0); PRIO0; BARR();                                        \
    RD_B(BUF, 1);                                                             \
    stageA((BUF), 0, (KN2));       /* A0(t+2) over dead A0(t) */              \
    BARR(); LGKM0();                                                          \
    PRIO1; MFMA8(0, 1); PRIO0; BARR();                                        \
    RD_A(BUF, 1);                                                             \
    stageB((BUF), 0, (KN2));       /* B0(t+2) over dead B0(t) */              \
    BARR(); LGKM0();                                                          \
    PRIO1; MFMA8(1, 1); PRIO0; BARR();                                        \
    stageB((BUF), 1, (KN2));       /* B1(t+2) over dead B1(t) */              \
    PRIO1; MFMA8(1, 0); PRIO0;                                                \
    VMW(6); BARR();                /* forces ALL of t+1 (oldest 8) */         \
  }
  #define KTILE_PEN(BUF, KN1)                                                 \
  {                                                                           \
    RD_A(BUF, 0); RD_B(BUF, 0);                                               \
    stageA((BUF) ^ 1, 1, (KN1));                                              \
    LGKMW(8); BARR(); LGKM0();                                                \
    PRIO1; MFMA8(0, 0); PRIO0; BARR();                                        \
    RD_B(BUF, 1);                                                             \
    BARR(); LGKM0();                                                          \
    PRIO1; MFMA8(0, 1); PRIO0; BARR();                                        \
    RD_A(BUF, 1);                                                             \
    BARR(); LGKM0();                                                          \
    PRIO1; MFMA8(1, 1); PRIO0; BARR();                                        \
    PRIO1; MFMA8(1, 0); PRIO0;                                                \
    VMW(0); BARR();                                                           \
  }
  #define KTILE_LAST(BUF)                                                     \
  {                                                                           \
    RD_A(BUF, 0); RD_B(BUF, 0);                                               \
    BARR(); LGKM0();                                                          \
    PRIO1; MFMA8(0, 0); PRIO0; BARR();                                        \
    RD_B(BUF, 1);                                                             \
    BARR(); LGKM0();                                                          \
    PRIO1; MFMA8(0, 1); PRIO0; BARR();                                        \
    RD_A(BUF, 1);                                                             \
    BARR(); LGKM0();                                                          \
    PRIO1; MFMA8(1, 1); PRIO0; BARR();                                        \
    PRIO1; MFMA8(1, 0); PRIO0;                                                \
  }

  // deep prologue: t0 {A0,B0,B1,A1} + t1 {A0,B0,B1} = 14 loads; VMW(6)
  stageA(0, 0, 0);
  stageB(0, 0, 0);
  stageB(0, 1, 0);
  stageA(0, 1, 0);
  stageA(1, 0, 64);
  stageB(1, 0, 64);
  stageB(1, 1, 64);
  VMW(6); BARR();

  for (int it = 0; it < 15; ++it){
    KTILE_MAIN(0, (2 * it + 1) * 64, (2 * it + 2) * 64);
    KTILE_MAIN(1, (2 * it + 2) * 64, (2 * it + 3) * 64);
  }
  KTILE_PEN(0, 31 * 64);
  KTILE_LAST(1);

  // ---- epilogue ---- 32x32 C/D: col = lane&31, row = (r&3)+8*(r>>2)+4*(lane>>5)
  if constexpr (EPI == 0){
    unsigned short* C = (unsigned short*)Cb + (long)bz * Cbs;
    #pragma unroll
    for (int qm = 0; qm < 2; ++qm)
      #pragma unroll
      for (int qn = 0; qn < 2; ++qn)
        #pragma unroll
        for (int fa = 0; fa < 2; ++fa){
          const long col = tn + qn * 128 + wn * 32 + l31;
          #pragma unroll
          for (int r = 0; r < 16; ++r){
            const long row = tm + qm * 128 + wm * 64 + fa * 32
                           + (r & 3) + 8 * (r >> 2) + 4 * l32;
            C[row * LD + col] = f2bf(acc[qm][qn][fa][r] * scale);
          }
        }
  } else {
    float* C = (float*)Cb + (long)bz * Cbs;
    #pragma unroll
    for (int qm = 0; qm < 2; ++qm)
      #pragma unroll
      for (int qn = 0; qn < 2; ++qn)
        #pragma unroll
        for (int fa = 0; fa < 2; ++fa){
          const long col = tn + qn * 128 + wn * 32 + l31;
          #pragma unroll
          for (int r = 0; r < 16; ++r){
            const long row = tm + qm * 128 + wm * 64 + fa * 32
                           + (r & 3) + 8 * (r >> 2) + 4 * l32;
            C[row * LD + col] = acc[qm][qn][fa][r];
          }
        }
  }
  #undef RD_A
  #undef RD_B
  #undef MFMA8
  #undef KTILE_MAIN
  #undef KTILE_PEN
  #undef KTILE_LAST
}

template<int EPI>
__global__ __launch_bounds__(512, 2)
void gemm256(const unsigned short* __restrict__ A, const unsigned short* __restrict__ B,
             void* __restrict__ Cb, long Abs, long Bbs, long Cbs, float scale)
{
  __shared__ unsigned short lA[2][16384];
  __shared__ unsigned short lB[2][16384];
  int bx, by, bz; xcd_decode(bx, by, bz);
  gemm256_body<EPI>(A + (long)bz * Abs, B + (long)bz * Bbs, Cb, bz, Cbs,
                    (long)by * 256, (long)bx * 256, scale, lA, lB);
}

// fused U + V^T: z 0-3 -> U = NT(enc_q_b, Mt), z 4-7 -> V^T = NT(Wv, x_b)
__global__ __launch_bounds__(512, 2)
void gemm256_proj2(const unsigned short* A0, const unsigned short* A1,
                   const unsigned short* B0, const unsigned short* B1,
                   void* C0, void* C1)
{
  __shared__ unsigned short lA[2][16384];
  __shared__ unsigned short lB[2][16384];
  int bx, by, bz; xcd_decode(bx, by, bz);
  const int sec = bz >> 2, b = bz & 3;
  const long NN = (long)SQL * 2048;
  const unsigned short* Av = sec ? A1 : A0;
  const unsigned short* Bv = sec ? B1 : B0;
  void*                 Cv = sec ? C1 : C0;
  const long Abs = sec ? 0 : NN;   // Wv shared / enc_q batched
  const long Bbs = sec ? NN : 0;   // x batched / Mt shared
  gemm256_body<0>(Av + (long)b * Abs, Bv + (long)b * Bbs, Cv, b, NN,
                  (long)by * 256, (long)bx * 256, 1.f, lA, lB);
}

// ============ 128x128 4-wave GEMM (round-4 proven; splitk + fallback) ============
template<int AMODE, int BMODE, int EPI>
__device__ __forceinline__ void gemm_body(
    const void* __restrict__ Av, const void* __restrict__ Bv,
    void* __restrict__ Cb, int bz, long Abs, long Bbs, long Cbs,
    long tm, long tn, float scale, int koff, int klen,
    unsigned short (*lA)[4096], unsigned short (*lB)[4096])
{
  constexpr int LD = 2048;
  const int tid = threadIdx.x, lane = tid & 63, wave = tid >> 6;
  const int wr = wave >> 1, wc = wave & 1;
  const int c0 = tid, c1 = tid + 256;
  const int r0 = c0 >> 2, q0 = (c0 & 3) * 8;
  const int r1 = c1 >> 2, q1 = (c1 & 3) * 8;

  const unsigned short* A16 = (const unsigned short*)Av + (long)bz * Abs;
  const unsigned short* B16 = (const unsigned short*)Bv + (long)bz * Bbs;
  const float*          A32 = (const float*)Av + (long)bz * Abs;
  const float*          B32 = (const float*)Bv + (long)bz * Bbs;

  f32x4 acc[4][4] = {};
  f32x4 sA[4], sB[4];

  auto issueA = [&](int buf, int kk){
    if constexpr (AMODE == 0){
      __builtin_amdgcn_global_load_lds((const AS1 void*)(A16 + (tm + r0) * LD + q0 + kk),
                                       (AS3 void*)(lA[buf] + c0 * 8), 16, 0, 0);
      __builtin_amdgcn_global_load_lds((const AS1 void*)(A16 + (tm + r1) * LD + q1 + kk),
                                       (AS3 void*)(lA[buf] + c1 * 8), 16, 0, 0);
    } else {
      sA[0] = *(const f32x4*)(A32 + (tm + r0) * LD + q0 + kk);
      sA[1] = *(const f32x4*)(A32 + (tm + r0) * LD + q0 + kk + 4);
      sA[2] = *(const f32x4*)(A32 + (tm + r1) * LD + q1 + kk);
      sA[3] = *(const f32x4*)(A32 + (tm + r1) * LD + q1 + kk + 4);
    }
  };
  auto issueB = [&](int buf, int kk){
    if constexpr (BMODE == 0){
      __builtin_amdgcn_global_load_lds((const AS1 void*)(B16 + (tn + r0) * LD + q0 + kk),
                                       (AS3 void*)(lB[buf] + c0 * 8), 16, 0, 0);
      __builtin_amdgcn_global_load_lds((const AS1 void*)(B16 + (tn + r1) * LD + q1 + kk),
                                       (AS3 void*)(lB[buf] + c1 * 8), 16, 0, 0);
    } else {
      sB[0] = *(const f32x4*)(B32 + (tn + r0) * LD + q0 + kk);
      sB[1] = *(const f32x4*)(B32 + (tn + r0) * LD + q0 + kk + 4);
      sB[2] = *(const f32x4*)(B32 + (tn + r1) * LD + q1 + kk);
      sB[3] = *(const f32x4*)(B32 + (tn + r1) * LD + q1 + kk + 4);
    }
  };
  auto writeA = [&](int buf){
    if constexpr (AMODE == 1){
      ushort8 w0, w1;
      #pragma unroll
      for (int j = 0; j < 4; ++j){
        w0[j] = f2bf(sA[0][j]); w0[j + 4] = f2bf(sA[1][j]);
        w1[j] = f2bf(sA[2][j]); w1[j + 4] = f2bf(sA[3][j]);
      }
      *(ushort8*)(lA[buf] + c0 * 8) = w0;
      *(ushort8*)(lA[buf] + c1 * 8) = w1;
    }
  };
  auto writeB = [&](int buf){
    if constexpr (BMODE == 1){
      ushort8 w0, w1;
      #pragma unroll
      for (int j = 0; j < 4; ++j){
        w0[j] = f2bf(sB[0][j]); w0[j + 4] = f2bf(sB[1][j]);
        w1[j] = f2bf(sB[2][j]); w1[j + 4] = f2bf(sB[3][j]);
      }
      *(ushort8*)(lB[buf] + c0 * 8) = w0;
      *(ushort8*)(lB[buf] + c1 * 8) = w1;
    }
  };
  auto computeTile = [&](int buf){
    short8 aF[4], bF[4];
    #pragma unroll
    for (int m = 0; m < 4; ++m)
      aF[m] = *(const short8*)(lA[buf] + (wr * 64 + m * 16 + (lane & 15)) * 32 + (lane >> 4) * 8);
    #pragma unroll
    for (int n = 0; n < 4; ++n)
      bF[n] = *(const short8*)(lB[buf] + (wc * 64 + n * 16 + (lane & 15)) * 32 + (lane >> 4) * 8);
    #pragma unroll
    for (int m = 0; m < 4; ++m)
      #pragma unroll
      for (int n = 0; n < 4; ++n)
        acc[m][n] = __builtin_amdgcn_mfma_f32_16x16x32_bf16(aF[m], bF[n], acc[m][n], 0, 0, 0);
  };

  issueA(0, koff); issueB(0, koff); writeA(0); writeB(0);
  __syncthreads();
  int cur = 0;
  for (int k0 = koff; k0 < koff + klen - 32; k0 += 32){
    issueA(cur ^ 1, k0 + 32);
    issueB(cur ^ 1, k0 + 32);
    computeTile(cur);
    writeA(cur ^ 1); writeB(cur ^ 1);
    __syncthreads();
    cur ^= 1;
  }
  computeTile(cur);

  const int colo = lane & 15, rowg = (lane >> 4) * 4;
  if constexpr (EPI == 0){
    unsigned short* C = (unsigned short*)Cb + (long)bz * Cbs;
    #pragma unroll
    for (int m = 0; m < 4; ++m)
      #pragma unroll
      for (int j = 0; j < 4; ++j){
        const long row = tm + wr * 64 + m * 16 + rowg + j;
        unsigned short* cr = C + row * LD + tn + wc * 64 + colo;
        #pragma unroll
        for (int n = 0; n < 4; ++n) cr[n * 16] = f2bf(acc[m][n][j] * scale);
      }
  } else {
    float* C = (float*)Cb + (long)bz * Cbs;
    #pragma unroll
    for (int m = 0; m < 4; ++m)
      #pragma unroll
      for (int j = 0; j < 4; ++j){
        const long row = tm + wr * 64 + m * 16 + rowg + j;
        float* cr = C + row * LD + tn + wc * 64 + colo;
        #pragma unroll
        for (int n = 0; n < 4; ++n) cr[n * 16] = acc[m][n][j];
      }
  }
}

template<int AMODE, int BMODE, int EPI>
__global__ __launch_bounds__(256, 2)
void gemm_nt(const void* __restrict__ Abv, const void* __restrict__ Bbv,
             void* __restrict__ Cb, long Abs, long Bbs, long Cbs, float scale)
{
  __shared__ unsigned short lA[2][4096];
  __shared__ unsigned short lB[2][4096];
  int bx, by, bz; xcd_decode(bx, by, bz);
  gemm_body<AMODE, BMODE, EPI>(Abv, Bbv, Cb, bz, Abs, Bbs, Cbs,
                               (long)by * 128, (long)bx * 128, scale, 0, 2048, lA, lB);
}

// split-K Mt partial: grid (16,16,4); slice bz covers K [bz*512, +512) -> f32 partials.
__global__ __launch_bounds__(256, 2)
void gemm_splitk(const unsigned short* __restrict__ A, const unsigned short* __restrict__ B,
                 float* __restrict__ Cp)
{
  __shared__ unsigned short lA[2][4096];
  __shared__ unsigned short lB[2][4096];
  int bx, by, bz; xcd_decode(bx, by, bz);
  gemm_body<0, 0, 2>(A, B, Cp + (long)bz * 4194304, 0, 0, 0, 4194304,
                     (long)by * 128, (long)bx * 128, 1.f, bz * 512, 512, lA, lB);
}

// Mt = f2bf(scale * (P0+P1+P2+P3))
__global__ __launch_bounds__(256)
void mt_reduce(const float* __restrict__ Cp, unsigned short* __restrict__ Mt, float scale){
  for (long c = (long)blockIdx.x * blockDim.x + threadIdx.x; c < 1048576;
       c += (long)gridDim.x * blockDim.x){
    f32x4 a = ((const f32x4*)Cp)[c];
    f32x4 b = ((const f32x4*)(Cp + 4194304))[c];
    f32x4 d = ((const f32x4*)(Cp + 8388608))[c];
    f32x4 e = ((const f32x4*)(Cp + 12582912))[c];
    ushort4v w;
    #pragma unroll
    for (int j = 0; j < 4; ++j) w[j] = f2bf((a[j] + b[j] + d[j] + e[j]) * scale);
    ((ushort4v*)Mt)[c] = w;
  }
}

// fallback projections (f32 reg-staged)
__global__ __launch_bounds__(256, 2)
void gemm_proj3f(const void* A0, const void* A1, const void* A2,
                 const void* B0, const void* B1, const void* B2,
                 void* C0, void* C1, void* C2)
{
  __shared__ unsigned short lA[2][4096];
  __shared__ unsigned short lB[2][4096];
  int bx, by, bz; xcd_decode(bx, by, bz);
  const int sec = bz >> 2, b = bz & 3;
  const long NN = (long)SQL * 2048;
  const void* Av = sec == 0 ? A0 : sec == 1 ? A1 : A2;
  const void* Bv = sec == 0 ? B0 : sec == 1 ? B1 : B2;
  void*       Cv = sec == 0 ? C0 : sec == 1 ? C1 : C2;
  const long Abs = (sec == 2) ? 0 : NN;
  const long Bbs = (sec == 2) ? NN : 0;
  gemm_body<1, 1, 0>(Av, Bv, Cv, b, Abs, Bbs, NN,
                     (long)by * 128, (long)bx * 128, 1.f, 0, 2048, lA, lB);
}

// ------- row softmax with fused mask: S bf16 + mask row -> P bf16 -------
__global__ __launch_bounds__(256, 4)
void softmax_rows(const unsigned short* __restrict__ S, const void* __restrict__ mask,
                  const int* __restrict__ cnt, unsigned short* __restrict__ P){
  const long row = blockIdx.x;
  const int t = threadIdx.x;
  const int a0 = cnt[0], a1 = cnt[1], a2 = cnt[2];
  const int mmode = (a1 == 0) ? (a0 > 1000 ? 0 : 1) : (a2 > 1000 ? 2 : 3);

  ushort8 u = *((const ushort8*)(S + row * SKL) + t);
  float v[8];
  #pragma unroll
  for (int j = 0; j < 8; ++j) v[j] = bf2f(u[j]);

  const long mb = row * SKL + (long)t * 8;
  if (mmode == 0){
    uchar4 m0 = ((const uchar4*)mask)[mb / 4], m1 = ((const uchar4*)mask)[mb / 4 + 1];
    if (m0.x) v[0] = NEGV; if (m0.y) v[1] = NEGV; if (m0.z) v[2] = NEGV; if (m0.w) v[3] = NEGV;
    if (m1.x) v[4] = NEGV; if (m1.y) v[5] = NEGV; if (m1.z) v[6] = NEGV; if (m1.w) v[7] = NEGV;
  } else if (mmode == 1){
    int4 m0 = ((const int4*)mask)[mb / 4], m1 = ((const int4*)mask)[mb / 4 + 1];
    if (m0.x) v[0] = NEGV; if (m0.y) v[1] = NEGV; if (m0.z) v[2] = NEGV; if (m0.w) v[3] = NEGV;
    if (m1.x) v[4] = NEGV; if (m1.y) v[5] = NEGV; if (m1.z) v[6] = NEGV; if (m1.w) v[7] = NEGV;
  } else if (mmode == 2){
    ushort8 m = ((const ushort8*)mask)[mb / 8];
    #pragma unroll
    for (int j = 0; j < 8; ++j) if (m[j]) v[j] = NEGV;
  } else {
    f32x4 m0 = ((const f32x4*)mask)[mb / 4], m1 = ((const f32x4*)mask)[mb / 4 + 1];
    #pragma unroll
    for (int j = 0; j < 4; ++j){ if (m0[j] != 0.f) v[j] = NEGV; if (m1[j] != 0.f) v[4 + j] = NEGV; }
  }

  float mx = v[0];
  #pragma unroll
  for (int j = 1; j < 8; ++j) mx = fmaxf(mx, v[j]);
  #pragma unroll
  for (int o = 32; o >= 1; o >>= 1) mx = fmaxf(mx, __shfl_xor(mx, o));
  __shared__ float red[8];
  const int wv = t >> 6, ln = t & 63;
  if (ln == 0) red[wv] = mx;
  __syncthreads();
  mx = fmaxf(fmaxf(red[0], red[1]), fmaxf(red[2], red[3]));
  float e[8], sum = 0.f;
  #pragma unroll
  for (int j = 0; j < 8; ++j){ e[j] = exp2f((v[j] - mx) * 1.4426950408889634f); sum += e[j]; }
  #pragma unroll
  for (int o = 32; o >= 1; o >>= 1) sum += __shfl_xor(sum, o);
  if (ln == 0) red[4 + wv] = sum;
  __syncthreads();
  sum = red[4] + red[5] + red[6] + red[7];
  const float inv = 1.0f / sum;
  ushort8 o8;
  #pragma unroll
  for (int j = 0; j < 8; ++j) o8[j] = f2bf(e[j] * inv);
  *((ushort8*)(P + row * SKL) + t) = o8;
}

// ---------------- host ----------------
extern "C" void kernel_launch(void* const* d_in, const int* in_sizes, int n_in,
                              void* d_out, int out_size, void* d_ws, size_t ws_size,
                              hipStream_t stream)
{
  (void)in_sizes; (void)n_in; (void)out_size;
  const void* x    = d_in[0];
  const void* encq = d_in[1];
  const void* enck = d_in[2];
  const void* imsk = d_in[3];
  const void* Wq   = d_in[4];
  const void* Wk   = d_in[5];
  const void* Wv   = d_in[6];

  uint8_t* ws = (uint8_t*)d_ws;
  int* cnt = (int*)ws;
  const long NN = (long)2048 * 2048;
  const float scale = 0.022097086912079608f;  // 1/sqrt(2048)

  hipMemsetAsync(cnt, 0, 4096, stream);
  mask_detect<<<256, 256, 0, stream>>>((const uint8_t*)imsk, cnt);

  const size_t FULL_NEED = 4096 + 4ull * 33554432 + 4ull * 8388608; // 167,776,256
  if (ws_size >= FULL_NEED){
    unsigned short* xb  = (unsigned short*)(ws + 4096);
    unsigned short* qb  = xb  + 16777216;
    unsigned short* kb  = qb  + 16777216;
    unsigned short* Wvb = kb  + 16777216;
    unsigned short* WqT = Wvb + 4194304;
    unsigned short* WkT = WqT + 4194304;
    unsigned short* Mt  = WkT + 4194304;
    unsigned short* Vt  = Mt  + 4194304;
    unsigned short* U   = (unsigned short*)d_out;         // [0, 32MiB)
    unsigned short* S   = U + 16777216;                   // [32MiB, 64MiB)
    unsigned short* P   = qb;                             // qb dead after U

    prep<<<10240, 256, 0, stream>>>((const float*)x, (const float*)encq, (const float*)enck,
                                    (const float*)Wv, xb, qb, kb, Wvb,
                                    (const float*)Wq, (const float*)Wk, WqT, WkT);
    gemm_splitk<<<dim3(16, 16, 4), 256, 0, stream>>>(WkT, WqT, (float*)d_out);
    mt_reduce<<<1024, 256, 0, stream>>>((const float*)d_out, Mt, scale);
    gemm256_proj2<<<dim3(8, 8, 8), 512, 0, stream>>>(qb, Wvb, Mt, xb, U, Vt);
    gemm256<0><<<dim3(8, 8, BB), 512, 0, stream>>>(U, kb, S, NN, NN, NN, 1.f);
    softmax_rows<<<BB * SQL, 256, 0, stream>>>(S, imsk, cnt, P);
    gemm256<2><<<dim3(8, 8, BB), 512, 0, stream>>>(P, Vt, d_out, NN, NN, NN, 1.f);
  } else {
    unsigned short* Q  = (unsigned short*)(ws + 4096);
    unsigned short* Kp = Q  + 16777216;
    unsigned short* Vt = Kp + 16777216;
    unsigned short* P  = Q;
    unsigned short* S;
    const size_t need = 4096 + 4ull * 33554432;
    if (ws_size >= need) S = Vt + 16777216;
    else                 S = (unsigned short*)d_out;

    gemm_proj3f<<<dim3(16, 16, 12), 256, 0, stream>>>(encq, enck, Wv, Wq, Wk, x, Q, Kp, Vt);
    gemm_nt<0, 0, 0><<<dim3(16, 16, BB), 256, 0, stream>>>(Q, Kp, S, NN, NN, NN, scale);
    softmax_rows<<<BB * SQL, 256, 0, stream>>>(S, imsk, cnt, P);
    gemm_nt<0, 0, 2><<<dim3(16, 16, BB), 256, 0, stream>>>(P, Vt, d_out, NN, NN, NN, 1.f);
  }
}

// Round 15
// 450.574 us; speedup vs baseline: 1.0674x; 1.0674x over previous
//
#include <hip/hip_runtime.h>
#include <stdint.h>

typedef short  short8  __attribute__((ext_vector_type(8)));
typedef unsigned short ushort8 __attribute__((ext_vector_type(8)));
typedef unsigned short ushort4v __attribute__((ext_vector_type(4)));
typedef float  f32x4   __attribute__((ext_vector_type(4)));

#define BB  4
#define SQL 2048
#define SKL 2048
#define NEGV -1e9f
#define AS1 __attribute__((address_space(1)))
#define AS3 __attribute__((address_space(3)))

__device__ __forceinline__ unsigned short f2bf(float f){
  union { float f; uint32_t u; } x; x.f = f;
  return (unsigned short)((x.u + 0x7FFFu + ((x.u >> 16) & 1u)) >> 16);
}
__device__ __forceinline__ float bf2f(unsigned short h){
  union { uint32_t u; float f; } x; x.u = ((uint32_t)h) << 16;
  return x.f;
}

#define BARR() __builtin_amdgcn_s_barrier()
#define LGKM0() asm volatile("s_waitcnt lgkmcnt(0)" ::: "memory")
#define LGKMW(N) asm volatile("s_waitcnt lgkmcnt(" #N ")" ::: "memory")
#define VMW(N)  asm volatile("s_waitcnt vmcnt(" #N ")"   ::: "memory")
#define PRIO1 __builtin_amdgcn_s_setprio(1)
#define PRIO0 __builtin_amdgcn_s_setprio(0)

// ---------------- mask dtype sniffing ----------------
__global__ void mask_detect(const uint8_t* __restrict__ m, int* __restrict__ cnt){
  const long n4 = (long)BB * SQL * SKL / 4;
  long idx  = (long)blockIdx.x * blockDim.x + threadIdx.x;
  long step = (long)gridDim.x * blockDim.x;
  int c0 = 0, c1 = 0, c2 = 0;
  for (long i4 = idx; i4 < n4; i4 += step){
    uchar4 b = ((const uchar4*)m)[i4];
    c0 += (b.y != 0) + (b.z != 0) + (b.w != 0);
    c1 += (b.x > 1) + (b.y > 1) + (b.z > 1) + (b.w > 1);
    c2 += (b.y != 0);
  }
  #pragma unroll
  for (int o = 32; o >= 1; o >>= 1){
    c0 += __shfl_xor(c0, o); c1 += __shfl_xor(c1, o); c2 += __shfl_xor(c2, o);
  }
  if ((threadIdx.x & 63) == 0){
    atomicAdd(&cnt[0], c0); atomicAdd(&cnt[1], c1); atomicAdd(&cnt[2], c2);
  }
}

// ------ prep: fused {f32->bf16 cvt of x, enc_q, enc_k, Wv} + {transpose-cvt Wq, Wk} ------
__global__ __launch_bounds__(256)
void prep(const float* __restrict__ s0, const float* __restrict__ s1,
          const float* __restrict__ s2, const float* __restrict__ s3,
          unsigned short* __restrict__ d0, unsigned short* __restrict__ d1,
          unsigned short* __restrict__ d2, unsigned short* __restrict__ d3,
          const float* __restrict__ tq, const float* __restrict__ tk,
          unsigned short* __restrict__ dq, unsigned short* __restrict__ dk)
{
  if (blockIdx.x < 2048){
    const long total = 6815744;  // 3*2097152 + 524288 chunks of 8
    for (long c = (long)blockIdx.x * 256 + threadIdx.x; c < total; c += 2048 * 256){
      const float* s; unsigned short* d; long off;
      if      (c < 2097152){ s = s0; d = d0; off = c; }
      else if (c < 4194304){ s = s1; d = d1; off = c - 2097152; }
      else if (c < 6291456){ s = s2; d = d2; off = c - 4194304; }
      else                 { s = s3; d = d3; off = c - 6291456; }
      f32x4 a = ((const f32x4*)s)[off * 2];
      f32x4 b = ((const f32x4*)s)[off * 2 + 1];
      ushort8 w;
      #pragma unroll
      for (int j = 0; j < 4; ++j){ w[j] = f2bf(a[j]); w[j + 4] = f2bf(b[j]); }
      ((ushort8*)d)[off] = w;
    }
  } else {
    __shared__ float t[32][33];
    const int j = blockIdx.x - 2048;           // [0, 8192)
    const int z = j >> 12, rem = j & 4095;
    const float* s = z ? tk : tq;
    unsigned short* d = z ? dk : dq;
    const long bx = (long)(rem & 63) * 32, by = (long)(rem >> 6) * 32;
    const int tx = threadIdx.x & 31, ty = threadIdx.x >> 5;   // 32 x 8
    #pragma unroll
    for (int jj = 0; jj < 4; ++jj)
      t[ty + jj * 8][tx] = s[(by + ty + jj * 8) * 2048 + bx + tx];
    __syncthreads();
    #pragma unroll
    for (int jj = 0; jj < 4; ++jj)
      d[(bx + ty + jj * 8) * 2048 + by + tx] = f2bf(t[tx][ty + jj * 8]);
  }
}

// bijective XCD swizzle (nwg % 8 == 0 for all our grids)
__device__ __forceinline__ void xcd_decode(int& bx, int& by, int& bz){
  const int gx = gridDim.x, gy = gridDim.y;
  const int nwg = gx * gy * gridDim.z;
  const int lid = blockIdx.x + gx * (blockIdx.y + gy * blockIdx.z);
  const int sw  = (lid & 7) * (nwg >> 3) + (lid >> 3);
  bx = sw % gx;
  const int t = sw / gx;
  by = t % gy;
  bz = t / gy;
}

// ====== 256x256 NT GEMM — m201 schedule, 16x16x32 MFMA (round-13, 454.0us) ======
// Deep prologue: 7 half-tiles staged (t0 all + t1 {A0,B0,B1}), VMW(6).
// Per tile t: ph1 stage A1(t+1); ph2 stage A0(t+2) over dead A0(t);
// ph3 stage B0(t+2); ph4 stage B1(t+2); single VMW(6) at ph4-end.
// EPI: 0 = bf16 C (scaled); 2 = f32 C.
template<int EPI>
__device__ __forceinline__ void gemm256_body(
    const unsigned short* __restrict__ Ag, const unsigned short* __restrict__ Bg,
    void* __restrict__ Cb, int bz, long Cbs, long tm, long tn, float scale,
    unsigned short (&lA)[2][16384], unsigned short (&lB)[2][16384])
{
  constexpr int LD = 2048;
  const int tid = threadIdx.x, lane = tid & 63, wid = tid >> 6;
  const int wm = wid >> 2, wn = wid & 3;
  const int l15 = lane & 15, l16 = lane >> 4;

  f32x4 acc[2][2][4][2] = {};   // [qm][qn][mr][nr]
  short8 aF[4][2];
  short8 bF[2][2][2];

  auto stageA = [&](int buf, int half, int k){
    const unsigned short* s = Ag + (tm + half * 128) * LD + k;
    unsigned short* d = lA[buf] + half * 8192;
    #pragma unroll
    for (int l = 0; l < 2; ++l){
      const int idx = l * 512 + tid;
      const int r   = idx >> 3;
      const int gsw = (idx & 7) ^ (r & 7);
      __builtin_amdgcn_global_load_lds((const AS1 void*)(s + r * LD + gsw * 8),
                                       (AS3 void*)(d + idx * 8), 16, 0, 0);
    }
  };
  auto stageB = [&](int buf, int half, int k){
    const unsigned short* s = Bg + (tn + half * 128) * LD + k;
    unsigned short* d = lB[buf] + half * 8192;
    #pragma unroll
    for (int l = 0; l < 2; ++l){
      const int idx = l * 512 + tid;
      const int r   = idx >> 3;
      const int gsw = (idx & 7) ^ (r & 7);
      __builtin_amdgcn_global_load_lds((const AS1 void*)(s + r * LD + gsw * 8),
                                       (AS3 void*)(d + idx * 8), 16, 0, 0);
    }
  };

  #define RD_A(BUF, QM)                                                       \
    _Pragma("unroll")                                                         \
    for (int mr = 0; mr < 4; ++mr)                                            \
      _Pragma("unroll")                                                       \
      for (int ks = 0; ks < 2; ++ks){                                         \
        const int r = (QM) * 128 + wm * 64 + mr * 16 + l15;                   \
        const int g = ks * 4 + l16;                                           \
        aF[mr][ks] = *(const short8*)&lA[(BUF)][(r * 8 + (g ^ (r & 7))) * 8]; \
      }
  #define RD_B(BUF, QN)                                                       \
    _Pragma("unroll")                                                         \
    for (int nr = 0; nr < 2; ++nr)                                            \
      _Pragma("unroll")                                                       \
      for (int ks = 0; ks < 2; ++ks){                                         \
        const int c = (QN) * 128 + wn * 32 + nr * 16 + l15;                   \
        const int g = ks * 4 + l16;                                           \
        bF[QN][nr][ks] = *(const short8*)&lB[(BUF)][(c * 8 + (g ^ (c & 7))) * 8]; \
      }
  #define MFMA16(QM, QN)                                                      \
    _Pragma("unroll")                                                         \
    for (int mr = 0; mr < 4; ++mr)                                            \
      _Pragma("unroll")                                                       \
      for (int nr = 0; nr < 2; ++nr)                                          \
        _Pragma("unroll")                                                     \
        for (int ks = 0; ks < 2; ++ks)                                        \
          acc[QM][QN][mr][nr] = __builtin_amdgcn_mfma_f32_16x16x32_bf16(      \
              aF[mr][ks], bF[QN][nr][ks], acc[QM][QN][mr][nr], 0, 0, 0);

  // tile t in BUF; KN1 = (t+1)*64, KN2 = (t+2)*64
  #define KTILE_MAIN(BUF, KN1, KN2)                                           \
  {                                                                           \
    RD_A(BUF, 0); RD_B(BUF, 0);                                               \
    stageA((BUF) ^ 1, 1, (KN1));   /* A1(t+1): completes t+1 */               \
    LGKMW(8); BARR(); LGKM0();                                                \
    PRIO1; MFMA16(0, 0); PRIO0; BARR();                                       \
    RD_B(BUF, 1);                                                             \
    stageA((BUF), 0, (KN2));       /* A0(t+2) over dead A0(t) */              \
    BARR(); LGKM0();                                                          \
    PRIO1; MFMA16(0, 1); PRIO0; BARR();                                       \
    RD_A(BUF, 1);                                                             \
    stageB((BUF), 0, (KN2));       /* B0(t+2) over dead B0(t) */              \
    BARR(); LGKM0();                                                          \
    PRIO1; MFMA16(1, 1); PRIO0; BARR();                                       \
    stageB((BUF), 1, (KN2));       /* B1(t+2) over dead B1(t) */              \
    PRIO1; MFMA16(1, 0); PRIO0;                                               \
    VMW(6); BARR();                /* forces ALL of t+1 (oldest 8) */         \
  }
  #define KTILE_PEN(BUF, KN1)                                                 \
  {                                                                           \
    RD_A(BUF, 0); RD_B(BUF, 0);                                               \
    stageA((BUF) ^ 1, 1, (KN1));                                              \
    LGKMW(8); BARR(); LGKM0();                                                \
    PRIO1; MFMA16(0, 0); PRIO0; BARR();                                       \
    RD_B(BUF, 1);                                                             \
    BARR(); LGKM0();                                                          \
    PRIO1; MFMA16(0, 1); PRIO0; BARR();                                       \
    RD_A(BUF, 1);                                                             \
    BARR(); LGKM0();                                                          \
    PRIO1; MFMA16(1, 1); PRIO0; BARR();                                       \
    PRIO1; MFMA16(1, 0); PRIO0;                                               \
    VMW(0); BARR();                                                           \
  }
  #define KTILE_LAST(BUF)                                                     \
  {                                                                           \
    RD_A(BUF, 0); RD_B(BUF, 0);                                               \
    BARR(); LGKM0();                                                          \
    PRIO1; MFMA16(0, 0); PRIO0; BARR();                                       \
    RD_B(BUF, 1);                                                             \
    BARR(); LGKM0();                                                          \
    PRIO1; MFMA16(0, 1); PRIO0; BARR();                                       \
    RD_A(BUF, 1);                                                             \
    BARR(); LGKM0();                                                          \
    PRIO1; MFMA16(1, 1); PRIO0; BARR();                                       \
    PRIO1; MFMA16(1, 0); PRIO0;                                               \
  }

  // deep prologue: t0 {A0,B0,B1,A1} + t1 {A0,B0,B1} = 14 loads; VMW(6)
  stageA(0, 0, 0);
  stageB(0, 0, 0);
  stageB(0, 1, 0);
  stageA(0, 1, 0);
  stageA(1, 0, 64);
  stageB(1, 0, 64);
  stageB(1, 1, 64);
  VMW(6); BARR();

  for (int it = 0; it < 15; ++it){
    KTILE_MAIN(0, (2 * it + 1) * 64, (2 * it + 2) * 64);
    KTILE_MAIN(1, (2 * it + 2) * 64, (2 * it + 3) * 64);
  }
  KTILE_PEN(0, 31 * 64);
  KTILE_LAST(1);

  // ---- epilogue ---- C/D layout: col = lane&15, row = (lane>>4)*4 + j
  const int colo = l15, rowg = l16 * 4;
  if constexpr (EPI == 0){
    unsigned short* C = (unsigned short*)Cb + (long)bz * Cbs;
    #pragma unroll
    for (int qm = 0; qm < 2; ++qm)
      #pragma unroll
      for (int qn = 0; qn < 2; ++qn)
        #pragma unroll
        for (int mr = 0; mr < 4; ++mr)
          #pragma unroll
          for (int j = 0; j < 4; ++j){
            const long row = tm + qm * 128 + wm * 64 + mr * 16 + rowg + j;
            unsigned short* cr = C + row * LD + tn + qn * 128 + wn * 32 + colo;
            #pragma unroll
            for (int nr = 0; nr < 2; ++nr) cr[nr * 16] = f2bf(acc[qm][qn][mr][nr][j] * scale);
          }
  } else {
    float* C = (float*)Cb + (long)bz * Cbs;
    #pragma unroll
    for (int qm = 0; qm < 2; ++qm)
      #pragma unroll
      for (int qn = 0; qn < 2; ++qn)
        #pragma unroll
        for (int mr = 0; mr < 4; ++mr)
          #pragma unroll
          for (int j = 0; j < 4; ++j){
            const long row = tm + qm * 128 + wm * 64 + mr * 16 + rowg + j;
            float* cr = C + row * LD + tn + qn * 128 + wn * 32 + colo;
            #pragma unroll
            for (int nr = 0; nr < 2; ++nr) cr[nr * 16] = acc[qm][qn][mr][nr][j];
          }
  }
  #undef RD_A
  #undef RD_B
  #undef MFMA16
  #undef KTILE_MAIN
  #undef KTILE_PEN
  #undef KTILE_LAST
}

template<int EPI>
__global__ __launch_bounds__(512, 2)
void gemm256(const unsigned short* __restrict__ A, const unsigned short* __restrict__ B,
             void* __restrict__ Cb, long Abs, long Bbs, long Cbs, float scale)
{
  __shared__ unsigned short lA[2][16384];
  __shared__ unsigned short lB[2][16384];
  int bx, by, bz; xcd_decode(bx, by, bz);
  gemm256_body<EPI>(A + (long)bz * Abs, B + (long)bz * Bbs, Cb, bz, Cbs,
                    (long)by * 256, (long)bx * 256, scale, lA, lB);
}

// fused U + V^T: z 0-3 -> U = NT(enc_q_b, Mt), z 4-7 -> V^T = NT(Wv, x_b)
__global__ __launch_bounds__(512, 2)
void gemm256_proj2(const unsigned short* A0, const unsigned short* A1,
                   const unsigned short* B0, const unsigned short* B1,
                   void* C0, void* C1)
{
  __shared__ unsigned short lA[2][16384];
  __shared__ unsigned short lB[2][16384];
  int bx, by, bz; xcd_decode(bx, by, bz);
  const int sec = bz >> 2, b = bz & 3;
  const long NN = (long)SQL * 2048;
  const unsigned short* Av = sec ? A1 : A0;
  const unsigned short* Bv = sec ? B1 : B0;
  void*                 Cv = sec ? C1 : C0;
  const long Abs = sec ? 0 : NN;   // Wv shared / enc_q batched
  const long Bbs = sec ? NN : 0;   // x batched / Mt shared
  gemm256_body<0>(Av + (long)b * Abs, Bv + (long)b * Bbs, Cv, b, NN,
                  (long)by * 256, (long)bx * 256, 1.f, lA, lB);
}

// ============ 128x128 4-wave GEMM (round-4 proven; splitk + fallback) ============
template<int AMODE, int BMODE, int EPI>
__device__ __forceinline__ void gemm_body(
    const void* __restrict__ Av, const void* __restrict__ Bv,
    void* __restrict__ Cb, int bz, long Abs, long Bbs, long Cbs,
    long tm, long tn, float scale, int koff, int klen,
    unsigned short (*lA)[4096], unsigned short (*lB)[4096])
{
  constexpr int LD = 2048;
  const int tid = threadIdx.x, lane = tid & 63, wave = tid >> 6;
  const int wr = wave >> 1, wc = wave & 1;
  const int c0 = tid, c1 = tid + 256;
  const int r0 = c0 >> 2, q0 = (c0 & 3) * 8;
  const int r1 = c1 >> 2, q1 = (c1 & 3) * 8;

  const unsigned short* A16 = (const unsigned short*)Av + (long)bz * Abs;
  const unsigned short* B16 = (const unsigned short*)Bv + (long)bz * Bbs;
  const float*          A32 = (const float*)Av + (long)bz * Abs;
  const float*          B32 = (const float*)Bv + (long)bz * Bbs;

  f32x4 acc[4][4] = {};
  f32x4 sA[4], sB[4];

  auto issueA = [&](int buf, int kk){
    if constexpr (AMODE == 0){
      __builtin_amdgcn_global_load_lds((const AS1 void*)(A16 + (tm + r0) * LD + q0 + kk),
                                       (AS3 void*)(lA[buf] + c0 * 8), 16, 0, 0);
      __builtin_amdgcn_global_load_lds((const AS1 void*)(A16 + (tm + r1) * LD + q1 + kk),
                                       (AS3 void*)(lA[buf] + c1 * 8), 16, 0, 0);
    } else {
      sA[0] = *(const f32x4*)(A32 + (tm + r0) * LD + q0 + kk);
      sA[1] = *(const f32x4*)(A32 + (tm + r0) * LD + q0 + kk + 4);
      sA[2] = *(const f32x4*)(A32 + (tm + r1) * LD + q1 + kk);
      sA[3] = *(const f32x4*)(A32 + (tm + r1) * LD + q1 + kk + 4);
    }
  };
  auto issueB = [&](int buf, int kk){
    if constexpr (BMODE == 0){
      __builtin_amdgcn_global_load_lds((const AS1 void*)(B16 + (tn + r0) * LD + q0 + kk),
                                       (AS3 void*)(lB[buf] + c0 * 8), 16, 0, 0);
      __builtin_amdgcn_global_load_lds((const AS1 void*)(B16 + (tn + r1) * LD + q1 + kk),
                                       (AS3 void*)(lB[buf] + c1 * 8), 16, 0, 0);
    } else {
      sB[0] = *(const f32x4*)(B32 + (tn + r0) * LD + q0 + kk);
      sB[1] = *(const f32x4*)(B32 + (tn + r0) * LD + q0 + kk + 4);
      sB[2] = *(const f32x4*)(B32 + (tn + r1) * LD + q1 + kk);
      sB[3] = *(const f32x4*)(B32 + (tn + r1) * LD + q1 + kk + 4);
    }
  };
  auto writeA = [&](int buf){
    if constexpr (AMODE == 1){
      ushort8 w0, w1;
      #pragma unroll
      for (int j = 0; j < 4; ++j){
        w0[j] = f2bf(sA[0][j]); w0[j + 4] = f2bf(sA[1][j]);
        w1[j] = f2bf(sA[2][j]); w1[j + 4] = f2bf(sA[3][j]);
      }
      *(ushort8*)(lA[buf] + c0 * 8) = w0;
      *(ushort8*)(lA[buf] + c1 * 8) = w1;
    }
  };
  auto writeB = [&](int buf){
    if constexpr (BMODE == 1){
      ushort8 w0, w1;
      #pragma unroll
      for (int j = 0; j < 4; ++j){
        w0[j] = f2bf(sB[0][j]); w0[j + 4] = f2bf(sB[1][j]);
        w1[j] = f2bf(sB[2][j]); w1[j + 4] = f2bf(sB[3][j]);
      }
      *(ushort8*)(lB[buf] + c0 * 8) = w0;
      *(ushort8*)(lB[buf] + c1 * 8) = w1;
    }
  };
  auto computeTile = [&](int buf){
    short8 aF[4], bF[4];
    #pragma unroll
    for (int m = 0; m < 4; ++m)
      aF[m] = *(const short8*)(lA[buf] + (wr * 64 + m * 16 + (lane & 15)) * 32 + (lane >> 4) * 8);
    #pragma unroll
    for (int n = 0; n < 4; ++n)
      bF[n] = *(const short8*)(lB[buf] + (wc * 64 + n * 16 + (lane & 15)) * 32 + (lane >> 4) * 8);
    #pragma unroll
    for (int m = 0; m < 4; ++m)
      #pragma unroll
      for (int n = 0; n < 4; ++n)
        acc[m][n] = __builtin_amdgcn_mfma_f32_16x16x32_bf16(aF[m], bF[n], acc[m][n], 0, 0, 0);
  };

  issueA(0, koff); issueB(0, koff); writeA(0); writeB(0);
  __syncthreads();
  int cur = 0;
  for (int k0 = koff; k0 < koff + klen - 32; k0 += 32){
    issueA(cur ^ 1, k0 + 32);
    issueB(cur ^ 1, k0 + 32);
    computeTile(cur);
    writeA(cur ^ 1); writeB(cur ^ 1);
    __syncthreads();
    cur ^= 1;
  }
  computeTile(cur);

  const int colo = lane & 15, rowg = (lane >> 4) * 4;
  if constexpr (EPI == 0){
    unsigned short* C = (unsigned short*)Cb + (long)bz * Cbs;
    #pragma unroll
    for (int m = 0; m < 4; ++m)
      #pragma unroll
      for (int j = 0; j < 4; ++j){
        const long row = tm + wr * 64 + m * 16 + rowg + j;
        unsigned short* cr = C + row * LD + tn + wc * 64 + colo;
        #pragma unroll
        for (int n = 0; n < 4; ++n) cr[n * 16] = f2bf(acc[m][n][j] * scale);
      }
  } else {
    float* C = (float*)Cb + (long)bz * Cbs;
    #pragma unroll
    for (int m = 0; m < 4; ++m)
      #pragma unroll
      for (int j = 0; j < 4; ++j){
        const long row = tm + wr * 64 + m * 16 + rowg + j;
        float* cr = C + row * LD + tn + wc * 64 + colo;
        #pragma unroll
        for (int n = 0; n < 4; ++n) cr[n * 16] = acc[m][n][j];
      }
  }
}

template<int AMODE, int BMODE, int EPI>
__global__ __launch_bounds__(256, 2)
void gemm_nt(const void* __restrict__ Abv, const void* __restrict__ Bbv,
             void* __restrict__ Cb, long Abs, long Bbs, long Cbs, float scale)
{
  __shared__ unsigned short lA[2][4096];
  __shared__ unsigned short lB[2][4096];
  int bx, by, bz; xcd_decode(bx, by, bz);
  gemm_body<AMODE, BMODE, EPI>(Abv, Bbv, Cb, bz, Abs, Bbs, Cbs,
                               (long)by * 128, (long)bx * 128, scale, 0, 2048, lA, lB);
}

// split-K Mt partial: grid (16,16,4); slice bz covers K [bz*512, +512) -> f32 partials.
__global__ __launch_bounds__(256, 2)
void gemm_splitk(const unsigned short* __restrict__ A, const unsigned short* __restrict__ B,
                 float* __restrict__ Cp)
{
  __shared__ unsigned short lA[2][4096];
  __shared__ unsigned short lB[2][4096];
  int bx, by, bz; xcd_decode(bx, by, bz);
  gemm_body<0, 0, 2>(A, B, Cp + (long)bz * 4194304, 0, 0, 0, 4194304,
                     (long)by * 128, (long)bx * 128, 1.f, bz * 512, 512, lA, lB);
}

// Mt = f2bf(scale * (P0+P1+P2+P3))
__global__ __launch_bounds__(256)
void mt_reduce(const float* __restrict__ Cp, unsigned short* __restrict__ Mt, float scale){
  for (long c = (long)blockIdx.x * blockDim.x + threadIdx.x; c < 1048576;
       c += (long)gridDim.x * blockDim.x){
    f32x4 a = ((const f32x4*)Cp)[c];
    f32x4 b = ((const f32x4*)(Cp + 4194304))[c];
    f32x4 d = ((const f32x4*)(Cp + 8388608))[c];
    f32x4 e = ((const f32x4*)(Cp + 12582912))[c];
    ushort4v w;
    #pragma unroll
    for (int j = 0; j < 4; ++j) w[j] = f2bf((a[j] + b[j] + d[j] + e[j]) * scale);
    ((ushort4v*)Mt)[c] = w;
  }
}

// fallback projections (f32 reg-staged)
__global__ __launch_bounds__(256, 2)
void gemm_proj3f(const void* A0, const void* A1, const void* A2,
                 const void* B0, const void* B1, const void* B2,
                 void* C0, void* C1, void* C2)
{
  __shared__ unsigned short lA[2][4096];
  __shared__ unsigned short lB[2][4096];
  int bx, by, bz; xcd_decode(bx, by, bz);
  const int sec = bz >> 2, b = bz & 3;
  const long NN = (long)SQL * 2048;
  const void* Av = sec == 0 ? A0 : sec == 1 ? A1 : A2;
  const void* Bv = sec == 0 ? B0 : sec == 1 ? B1 : B2;
  void*       Cv = sec == 0 ? C0 : sec == 1 ? C1 : C2;
  const long Abs = (sec == 2) ? 0 : NN;
  const long Bbs = (sec == 2) ? NN : 0;
  gemm_body<1, 1, 0>(Av, Bv, Cv, b, Abs, Bbs, NN,
                     (long)by * 128, (long)bx * 128, 1.f, 0, 2048, lA, lB);
}

// ------- row softmax with fused mask: S bf16 + mask row -> P bf16 -------
__global__ __launch_bounds__(256, 4)
void softmax_rows(const unsigned short* __restrict__ S, const void* __restrict__ mask,
                  const int* __restrict__ cnt, unsigned short* __restrict__ P){
  const long row = blockIdx.x;
  const int t = threadIdx.x;
  const int a0 = cnt[0], a1 = cnt[1], a2 = cnt[2];
  // 0: uint8 bool, 1: int32, 2: bf16-coded, 3: f32-coded
  const int mmode = (a1 == 0) ? (a0 > 1000 ? 0 : 1) : (a2 > 1000 ? 2 : 3);

  ushort8 u = *((const ushort8*)(S + row * SKL) + t);
  float v[8];
  #pragma unroll
  for (int j = 0; j < 8; ++j) v[j] = bf2f(u[j]);

  const long mb = row * SKL + (long)t * 8;
  if (mmode == 0){
    uchar4 m0 = ((const uchar4*)mask)[mb / 4], m1 = ((const uchar4*)mask)[mb / 4 + 1];
    if (m0.x) v[0] = NEGV; if (m0.y) v[1] = NEGV; if (m0.z) v[2] = NEGV; if (m0.w) v[3] = NEGV;
    if (m1.x) v[4] = NEGV; if (m1.y) v[5] = NEGV; if (m1.z) v[6] = NEGV; if (m1.w) v[7] = NEGV;
  } else if (mmode == 1){
    int4 m0 = ((const int4*)mask)[mb / 4], m1 = ((const int4*)mask)[mb / 4 + 1];
    if (m0.x) v[0] = NEGV; if (m0.y) v[1] = NEGV; if (m0.z) v[2] = NEGV; if (m0.w) v[3] = NEGV;
    if (m1.x) v[4] = NEGV; if (m1.y) v[5] = NEGV; if (m1.z) v[6] = NEGV; if (m1.w) v[7] = NEGV;
  } else if (mmode == 2){
    ushort8 m = ((const ushort8*)mask)[mb / 8];
    #pragma unroll
    for (int j = 0; j < 8; ++j) if (m[j]) v[j] = NEGV;
  } else {
    f32x4 m0 = ((const f32x4*)mask)[mb / 4], m1 = ((const f32x4*)mask)[mb / 4 + 1];
    #pragma unroll
    for (int j = 0; j < 4; ++j){ if (m0[j] != 0.f) v[j] = NEGV; if (m1[j] != 0.f) v[4 + j] = NEGV; }
  }

  float mx = v[0];
  #pragma unroll
  for (int j = 1; j < 8; ++j) mx = fmaxf(mx, v[j]);
  #pragma unroll
  for (int o = 32; o >= 1; o >>= 1) mx = fmaxf(mx, __shfl_xor(mx, o));
  __shared__ float red[8];
  const int wv = t >> 6, ln = t & 63;
  if (ln == 0) red[wv] = mx;
  __syncthreads();
  mx = fmaxf(fmaxf(red[0], red[1]), fmaxf(red[2], red[3]));
  float e[8], sum = 0.f;
  #pragma unroll
  for (int j = 0; j < 8; ++j){ e[j] = exp2f((v[j] - mx) * 1.4426950408889634f); sum += e[j]; }
  #pragma unroll
  for (int o = 32; o >= 1; o >>= 1) sum += __shfl_xor(sum, o);
  if (ln == 0) red[4 + wv] = sum;
  __syncthreads();
  sum = red[4] + red[5] + red[6] + red[7];
  const float inv = 1.0f / sum;
  ushort8 o8;
  #pragma unroll
  for (int j = 0; j < 8; ++j) o8[j] = f2bf(e[j] * inv);
  *((ushort8*)(P + row * SKL) + t) = o8;
}

// ---------------- host ----------------
extern "C" void kernel_launch(void* const* d_in, const int* in_sizes, int n_in,
                              void* d_out, int out_size, void* d_ws, size_t ws_size,
                              hipStream_t stream)
{
  (void)in_sizes; (void)n_in; (void)out_size;
  const void* x    = d_in[0];
  const void* encq = d_in[1];
  const void* enck = d_in[2];
  const void* imsk = d_in[3];
  const void* Wq   = d_in[4];
  const void* Wk   = d_in[5];
  const void* Wv   = d_in[6];

  uint8_t* ws = (uint8_t*)d_ws;
  int* cnt = (int*)ws;
  const long NN = (long)2048 * 2048;
  const float scale = 0.022097086912079608f;  // 1/sqrt(2048)

  hipMemsetAsync(cnt, 0, 4096, stream);
  mask_detect<<<256, 256, 0, stream>>>((const uint8_t*)imsk, cnt);

  const size_t FULL_NEED = 4096 + 4ull * 33554432 + 4ull * 8388608; // 167,776,256
  if (ws_size >= FULL_NEED){
    unsigned short* xb  = (unsigned short*)(ws + 4096);
    unsigned short* qb  = xb  + 16777216;
    unsigned short* kb  = qb  + 16777216;
    unsigned short* Wvb = kb  + 16777216;
    unsigned short* WqT = Wvb + 4194304;
    unsigned short* WkT = WqT + 4194304;
    unsigned short* Mt  = WkT + 4194304;
    unsigned short* Vt  = Mt  + 4194304;
    unsigned short* U   = (unsigned short*)d_out;         // [0, 32MiB)
    unsigned short* S   = U + 16777216;                   // [32MiB, 64MiB)
    unsigned short* P   = qb;                             // qb dead after U

    prep<<<10240, 256, 0, stream>>>((const float*)x, (const float*)encq, (const float*)enck,
                                    (const float*)Wv, xb, qb, kb, Wvb,
                                    (const float*)Wq, (const float*)Wk, WqT, WkT);
    gemm_splitk<<<dim3(16, 16, 4), 256, 0, stream>>>(WkT, WqT, (float*)d_out);
    mt_reduce<<<1024, 256, 0, stream>>>((const float*)d_out, Mt, scale);
    gemm256_proj2<<<dim3(8, 8, 8), 512, 0, stream>>>(qb, Wvb, Mt, xb, U, Vt);
    gemm256<0><<<dim3(8, 8, BB), 512, 0, stream>>>(U, kb, S, NN, NN, NN, 1.f);
    softmax_rows<<<BB * SQL, 256, 0, stream>>>(S, imsk, cnt, P);
    gemm256<2><<<dim3(8, 8, BB), 512, 0, stream>>>(P, Vt, d_out, NN, NN, NN, 1.f);
  } else {
    unsigned short* Q  = (unsigned short*)(ws + 4096);
    unsigned short* Kp = Q  + 16777216;
    unsigned short* Vt = Kp + 16777216;
    unsigned short* P  = Q;
    unsigned short* S;
    const size_t need = 4096 + 4ull * 33554432;
    if (ws_size >= need) S = Vt + 16777216;
    else                 S = (unsigned short*)d_out;

    gemm_proj3f<<<dim3(16, 16, 12), 256, 0, stream>>>(encq, enck, Wv, Wq, Wk, x, Q, Kp, Vt);
    gemm_nt<0, 0, 0><<<dim3(16, 16, BB), 256, 0, stream>>>(Q, Kp, S, NN, NN, NN, scale);
    softmax_rows<<<BB * SQL, 256, 0, stream>>>(S, imsk, cnt, P);
    gemm_nt<0, 0, 2><<<dim3(16, 16, BB), 256, 0, stream>>>(P, Vt, d_out, NN, NN, NN, 1.f);
  }
}